// Round 1
// baseline (422.868 us; speedup 1.0000x reference)
//
#include <hip/hip_runtime.h>
#include <math.h>

// Problem constants (from setup_inputs)
#define BB   8
#define CXH  16
#define CXL  8
#define HH   256
#define HL   512

// Tiling
#define TS   32              // 512-res tile edge
#define HALO 2
#define GT   (TS + 2*HALO)   // 36 : LN'd tile + halo
#define QT   (TS/2)          // 16 : 256-res tile edge
#define DT   (QT + 2)        // 18 : 256-res tile + halo1

__device__ __forceinline__ float gelu_exact(float x) {
    return 0.5f * x * (1.0f + erff(x * 0.70710678118654752f));
}

__global__ __launch_bounds__(256, 2)
void uem_fused_kernel(const float* __restrict__ xh,
                      const float* __restrict__ xl,
                      const float* __restrict__ mask,
                      const float* __restrict__ pre_w,
                      const float* __restrict__ pre_b,
                      const float* __restrict__ g_ln_w,
                      const float* __restrict__ g_ln_b,
                      const float* __restrict__ g_base_w,
                      const float* __restrict__ g_base_b,
                      const float* __restrict__ g_base_s,
                      const float* __restrict__ g_wt_w,
                      const float* __restrict__ g_wt_s,
                      const float* __restrict__ g_pw_w,
                      const float* __restrict__ tail_ln_w,
                      const float* __restrict__ tail_ln_b,
                      const float* __restrict__ tail_w,
                      const float* __restrict__ tail_b,
                      const float* __restrict__ res_w,
                      const float* __restrict__ res_b,
                      float* __restrict__ out)
{
    // LDS: 6720 + 26640 + 27360 = 60720 B  -> 2 blocks/CU
    __shared__ float s_xhp[8][20][21];       // pre-projected xh patch (256-res)
    __shared__ float s_gln[5][GT][GT + 1];   // LN'd branch input, tile+halo2
    __shared__ float s_dwt[20][DT][DT + 1];  // DWT subbands (c*4+k), tile+halo1

    const int b   = blockIdx.z;
    const int ty0 = blockIdx.y * TS;
    const int tx0 = blockIdx.x * TS;
    const int tx  = threadIdx.x, ty = threadIdx.y;
    const int tid = ty * 16 + tx;

    const float SC = (float)(255.0 / 511.0);   // align_corners scale, f32-rounded as in JAX

    // ---------- Phase 0: 1x1 conv (16->8) of xh into the patch this tile's bilinear needs ----------
    const int r0y = max(ty0 - HALO, 0);
    const int r0x = max(tx0 - HALO, 0);
    int base_iy = min((int)((float)r0y * SC), HH - 20);   // clamp so 20 rows stay in-range
    int base_ix = min((int)((float)r0x * SC), HH - 20);

    for (int idx = tid; idx < 400; idx += 256) {
        const int py = idx / 20, px = idx % 20;
        const int iy = base_iy + py, ix = base_ix + px;
        const float* xp = xh + ((b * CXH) * HH + iy) * HH + ix;
        float xv[16];
        #pragma unroll
        for (int c = 0; c < 16; ++c) xv[c] = xp[c * HH * HH];
        #pragma unroll
        for (int oc = 0; oc < 8; ++oc) {
            float acc = pre_b[oc];
            #pragma unroll
            for (int c = 0; c < 16; ++c) acc += pre_w[oc * 16 + c] * xv[c];
            s_xhp[oc][py][px] = acc;
        }
    }
    __syncthreads();

    // Per-quad-pixel accumulators for tail LN + tail 1x1 pre-products
    float S1[4] = {0.f, 0.f, 0.f, 0.f};
    float S2[4] = {0.f, 0.f, 0.f, 0.f};
    float T[4][8];
    #pragma unroll
    for (int p = 0; p < 4; ++p)
        #pragma unroll
        for (int o = 0; o < 8; ++o) T[p][o] = 0.f;

    for (int br = 0; br < 4; ++br) {
        // ---------- Phase 1: build LN'd gi (tile + halo2) in LDS ----------
        for (int idx = tid; idx < GT * GT; idx += 256) {
            const int ly = idx / GT, lx = idx % GT;
            const int gy = ty0 - HALO + ly, gx = tx0 - HALO + lx;
            float vv[5] = {0.f, 0.f, 0.f, 0.f, 0.f};
            if (gy >= 0 && gy < HL && gx >= 0 && gx < HL) {
                // bilinear (align_corners=True) sample of xh_p, 2 channels
                const float cy = (float)gy * SC;
                int iy0 = min((int)cy, HH - 2);
                const float fy = cy - (float)iy0;
                const float cx = (float)gx * SC;
                int ix0 = min((int)cx, HH - 2);
                const float fx = cx - (float)ix0;
                const int liy = iy0 - base_iy, lix = ix0 - base_ix;
                #pragma unroll
                for (int k = 0; k < 2; ++k) {
                    const float p00 = s_xhp[2 * br + k][liy][lix];
                    const float p01 = s_xhp[2 * br + k][liy][lix + 1];
                    const float p10 = s_xhp[2 * br + k][liy + 1][lix];
                    const float p11 = s_xhp[2 * br + k][liy + 1][lix + 1];
                    const float top = p00 + fx * (p01 - p00);
                    const float bot = p10 + fx * (p11 - p10);
                    vv[k] = top + fy * (bot - top);
                }
                const int xbase = ((b * CXL) * HL + gy) * HL + gx;
                vv[2] = xl[xbase + (2 * br) * HL * HL];
                vv[3] = xl[xbase + (2 * br + 1) * HL * HL];
                vv[4] = mask[(b * HL + gy) * HL + gx];
                // channels-first LN over the 5 channels
                const float u = (vv[0] + vv[1] + vv[2] + vv[3] + vv[4]) * 0.2f;
                float var = 0.f;
                #pragma unroll
                for (int c = 0; c < 5; ++c) { const float d = vv[c] - u; var += d * d; }
                var *= 0.2f;
                const float rstd = rsqrtf(var + 1e-6f);
                #pragma unroll
                for (int c = 0; c < 5; ++c)
                    vv[c] = g_ln_w[br * 5 + c] * ((vv[c] - u) * rstd) + g_ln_b[br * 5 + c];
            }
            #pragma unroll
            for (int c = 0; c < 5; ++c) s_gln[c][ly][lx] = vv[c];
        }
        __syncthreads();

        // ---------- Phase 2: Haar DWT to 256-res (tile + halo1) ----------
        for (int idx = tid; idx < DT * DT; idx += 256) {
            const int l = idx / DT, m = idx % DT;
            #pragma unroll
            for (int c = 0; c < 5; ++c) {
                const float a  = s_gln[c][2 * l][2 * m];
                const float b2 = s_gln[c][2 * l][2 * m + 1];
                const float c2 = s_gln[c][2 * l + 1][2 * m];
                const float d2 = s_gln[c][2 * l + 1][2 * m + 1];
                s_dwt[c * 4 + 0][l][m] = 0.5f * (a + b2 + c2 + d2);  // LL
                s_dwt[c * 4 + 1][l][m] = 0.5f * (a + b2 - c2 - d2);  // LH
                s_dwt[c * 4 + 2][l][m] = 0.5f * (a - b2 + c2 - d2);  // HL
                s_dwt[c * 4 + 3][l][m] = 0.5f * (a - b2 - c2 + d2);  // HH
            }
        }
        __syncthreads();

        // ---------- Phase 3: depthwise 3x3 on subbands (per-thread 256-pos), scale ----------
        float tag[20];
        #pragma unroll
        for (int j = 0; j < 20; ++j) {
            const float* w = g_wt_w + br * 180 + j * 9;
            float acc = 0.f;
            #pragma unroll
            for (int dy = 0; dy < 3; ++dy)
                #pragma unroll
                for (int dx = 0; dx < 3; ++dx)
                    acc += w[dy * 3 + dx] * s_dwt[j][ty + dy][tx + dx];
            tag[j] = acc * g_wt_s[br * 20 + j];
        }

        // ---------- IDWT (thread-local 2x2 quad) ----------
        float xt[5][4];   // [channel][quad pixel p = py*2+px]
        #pragma unroll
        for (int c = 0; c < 5; ++c) {
            const float LL = tag[c * 4 + 0], LH = tag[c * 4 + 1];
            const float HLv = tag[c * 4 + 2], HHv = tag[c * 4 + 3];
            xt[c][0] = 0.5f * (LL + LH + HLv + HHv);
            xt[c][1] = 0.5f * (LL + LH - HLv - HHv);
            xt[c][2] = 0.5f * (LL - LH + HLv - HHv);
            xt[c][3] = 0.5f * (LL - LH - HLv + HHv);
        }

        // ---------- Phase 4: base 3x3 dwconv + combine + 5x5 pointwise + tail accumulation ----------
        #pragma unroll
        for (int p = 0; p < 4; ++p) {
            const int py = p >> 1, px = p & 1;
            const int r = HALO + 2 * ty + py, cc = HALO + 2 * tx + px;
            float gi[5];
            #pragma unroll
            for (int c = 0; c < 5; ++c) {
                const float* bw = g_base_w + br * 45 + c * 9;
                float acc = 0.f;
                #pragma unroll
                for (int dy = 0; dy < 3; ++dy)
                    #pragma unroll
                    for (int dx = 0; dx < 3; ++dx)
                        acc += bw[dy * 3 + dx] * s_gln[c][r + dy - 1][cc + dx - 1];
                gi[c] = (acc + g_base_b[br * 5 + c]) * g_base_s[br * 5 + c] + xt[c][p];
            }
            #pragma unroll
            for (int o = 0; o < 5; ++o) {
                float v = 0.f;
                #pragma unroll
                for (int c = 0; c < 5; ++c) v += g_pw_w[br * 25 + o * 5 + c] * gi[c];
                const int cg = br * 5 + o;
                S1[p] += v;
                S2[p] += v * v;
                const float lw = tail_ln_w[cg];
                #pragma unroll
                for (int o8 = 0; o8 < 8; ++o8)
                    T[p][o8] += tail_w[o8 * 20 + cg] * lw * v;
            }
        }
        __syncthreads();   // before next branch overwrites s_gln / s_dwt
    }

    // ---------- Phase 5: tail LN (closed form) + 1x1 + GELU + residual ----------
    float A[8], Bc[8];
    #pragma unroll
    for (int o = 0; o < 8; ++o) {
        float a = 0.f, bb = tail_b[o];
        #pragma unroll
        for (int cg = 0; cg < 20; ++cg) {
            a  += tail_w[o * 20 + cg] * tail_ln_w[cg];
            bb += tail_w[o * 20 + cg] * tail_ln_b[cg];
        }
        A[o] = a; Bc[o] = bb;
    }

    #pragma unroll
    for (int p = 0; p < 4; ++p) {
        const int py = p >> 1, px = p & 1;
        const int gy = ty0 + 2 * ty + py, gx = tx0 + 2 * tx + px;
        const float u    = S1[p] * 0.05f;
        const float var  = S2[p] * 0.05f - u * u;
        const float rstd = rsqrtf(var + 1e-6f);

        const int xbase = ((b * CXL) * HL + gy) * HL + gx;
        float xlv[8];
        #pragma unroll
        for (int c = 0; c < 8; ++c) xlv[c] = xl[xbase + c * HL * HL];
        const float mk = mask[(b * HL + gy) * HL + gx];

        #pragma unroll
        for (int o = 0; o < 8; ++o) {
            const float val = (T[p][o] - u * A[o]) * rstd + Bc[o];
            const float g = gelu_exact(val);
            float r = res_b[o] + res_w[o * 9 + 8] * mk;
            #pragma unroll
            for (int c = 0; c < 8; ++c) r += res_w[o * 9 + c] * xlv[c];
            out[xbase + o * HL * HL] = g + r;
        }
    }
}

extern "C" void kernel_launch(void* const* d_in, const int* in_sizes, int n_in,
                              void* d_out, int out_size, void* d_ws, size_t ws_size,
                              hipStream_t stream) {
    (void)in_sizes; (void)out_size; (void)d_ws; (void)ws_size;
    if (n_in < 19) return;
    const float* xh        = (const float*)d_in[0];
    const float* xl        = (const float*)d_in[1];
    const float* mask      = (const float*)d_in[2];
    const float* pre_w     = (const float*)d_in[3];
    const float* pre_b     = (const float*)d_in[4];
    const float* g_ln_w    = (const float*)d_in[5];
    const float* g_ln_b    = (const float*)d_in[6];
    const float* g_base_w  = (const float*)d_in[7];
    const float* g_base_b  = (const float*)d_in[8];
    const float* g_base_s  = (const float*)d_in[9];
    const float* g_wt_w    = (const float*)d_in[10];
    const float* g_wt_s    = (const float*)d_in[11];
    const float* g_pw_w    = (const float*)d_in[12];
    const float* tail_ln_w = (const float*)d_in[13];
    const float* tail_ln_b = (const float*)d_in[14];
    const float* tail_w    = (const float*)d_in[15];
    const float* tail_b    = (const float*)d_in[16];
    const float* res_w     = (const float*)d_in[17];
    const float* res_b     = (const float*)d_in[18];
    float* outp = (float*)d_out;

    dim3 grid(HL / TS, HL / TS, BB);   // (16, 16, 8) = 2048 blocks
    dim3 block(16, 16, 1);             // 256 threads, each owns a 2x2 quad
    uem_fused_kernel<<<grid, block, 0, stream>>>(
        xh, xl, mask, pre_w, pre_b, g_ln_w, g_ln_b, g_base_w, g_base_b,
        g_base_s, g_wt_w, g_wt_s, g_pw_w, tail_ln_w, tail_ln_b, tail_w,
        tail_b, res_w, res_b, outp);
}

// Round 2
// 372.455 us; speedup vs baseline: 1.1354x; 1.1354x over previous
//
#include <hip/hip_runtime.h>
#include <math.h>

// Problem constants (from setup_inputs)
#define BB   8
#define CXH  16
#define CXL  8
#define HH   256
#define HL   512

// Tiling
#define TS   32              // 512-res tile edge
#define HALO 2
#define GT   (TS + 2*HALO)   // 36 : LN'd tile + halo
#define GP   38              // padded (even) row pitch for s_gln -> b64-aligned
#define QT   (TS/2)          // 16 : 256-res tile edge
#define DT   (QT + 2)        // 18 : 256-res tile + halo1

__device__ __forceinline__ float gelu_exact(float x) {
    return 0.5f * x * (1.0f + erff(x * 0.70710678118654752f));
}

__global__ __launch_bounds__(256, 3)
void uem_fused_kernel(const float* __restrict__ xh,
                      const float* __restrict__ xl,
                      const float* __restrict__ mask,
                      const float* __restrict__ pre_w,
                      const float* __restrict__ pre_b,
                      const float* __restrict__ g_ln_w,
                      const float* __restrict__ g_ln_b,
                      const float* __restrict__ g_base_w,
                      const float* __restrict__ g_base_b,
                      const float* __restrict__ g_base_s,
                      const float* __restrict__ g_wt_w,
                      const float* __restrict__ g_wt_s,
                      const float* __restrict__ g_pw_w,
                      const float* __restrict__ tail_ln_w,
                      const float* __restrict__ tail_ln_b,
                      const float* __restrict__ tail_w,
                      const float* __restrict__ tail_b,
                      const float* __restrict__ res_w,
                      const float* __restrict__ res_b,
                      float* __restrict__ out)
{
    // LDS total = 27360 + 25920 = 53280 B  ->  3 blocks/CU (12 waves/CU)
    __shared__ __align__(16) float s_gln[5][GT][GP];   // LN'd branch input (planar, even pitch)
    // Union region: phase0b/1 uses it as xh-patch [20][20][2] (3200 B),
    // phase2/3 as DWT subbands [DT][DT][20] interleaved (25920 B).
    // Barriers between those phases make the lifetimes disjoint.
    __shared__ __align__(16) float s_un[DT * DT * 20];

    const int b   = blockIdx.z;
    const int ty0 = blockIdx.y * TS;
    const int tx0 = blockIdx.x * TS;
    const int tx  = threadIdx.x, ty = threadIdx.y;
    const int tid = ty * 16 + tx;

    const float SC = (float)(255.0 / 511.0);   // align_corners scale, f32 as in JAX

    const int r0y = max(ty0 - HALO, 0);
    const int r0x = max(tx0 - HALO, 0);
    const int base_iy = min((int)((float)r0y * SC), HH - 20);
    const int base_ix = min((int)((float)r0x * SC), HH - 20);

    // Per-quad-pixel accumulators for tail LN + tail 1x1 pre-products
    float S1[4] = {0.f, 0.f, 0.f, 0.f};
    float S2[4] = {0.f, 0.f, 0.f, 0.f};
    float T[4][8];
    #pragma unroll
    for (int p = 0; p < 4; ++p)
        #pragma unroll
        for (int o = 0; o < 8; ++o) T[p][o] = 0.f;

    for (int br = 0; br < 4; ++br) {
        // ---------- Phase 0b: 1x1 conv (16 -> 2 chans of this branch) into union patch ----------
        // Layout: s_un[(py*20+px)*2 + k]  (k = 0,1 -> channels 2br, 2br+1)
        for (int idx = tid; idx < 400; idx += 256) {
            const int py = idx / 20, px = idx % 20;
            const int iy = base_iy + py, ix = base_ix + px;
            const float* xp = xh + ((b * CXH) * HH + iy) * HH + ix;
            float xv[16];
            #pragma unroll
            for (int c = 0; c < 16; ++c) xv[c] = xp[c * HH * HH];
            float2 r;
            float a0 = pre_b[2 * br], a1 = pre_b[2 * br + 1];
            #pragma unroll
            for (int c = 0; c < 16; ++c) {
                a0 += pre_w[(2 * br) * 16 + c] * xv[c];
                a1 += pre_w[(2 * br + 1) * 16 + c] * xv[c];
            }
            r.x = a0; r.y = a1;
            *(float2*)&s_un[(py * 20 + px) * 2] = r;
        }
        __syncthreads();

        // ---------- Phase 1: build LN'd gi (tile + halo2) in LDS ----------
        for (int idx = tid; idx < GT * GT; idx += 256) {
            const int ly = idx / GT, lx = idx % GT;
            const int gy = ty0 - HALO + ly, gx = tx0 - HALO + lx;
            float vv[5] = {0.f, 0.f, 0.f, 0.f, 0.f};
            if (gy >= 0 && gy < HL && gx >= 0 && gx < HL) {
                const float cy = (float)gy * SC;
                const int iy0 = min((int)cy, HH - 2);
                const float fy = cy - (float)iy0;
                const float cx = (float)gx * SC;
                const int ix0 = min((int)cx, HH - 2);
                const float fx = cx - (float)ix0;
                const int liy = iy0 - base_iy, lix = ix0 - base_ix;
                const float2 q00 = *(const float2*)&s_un[((liy)     * 20 + lix)     * 2];
                const float2 q01 = *(const float2*)&s_un[((liy)     * 20 + lix + 1) * 2];
                const float2 q10 = *(const float2*)&s_un[((liy + 1) * 20 + lix)     * 2];
                const float2 q11 = *(const float2*)&s_un[((liy + 1) * 20 + lix + 1) * 2];
                {
                    const float top = q00.x + fx * (q01.x - q00.x);
                    const float bot = q10.x + fx * (q11.x - q10.x);
                    vv[0] = top + fy * (bot - top);
                }
                {
                    const float top = q00.y + fx * (q01.y - q00.y);
                    const float bot = q10.y + fx * (q11.y - q10.y);
                    vv[1] = top + fy * (bot - top);
                }
                const int xbase = ((b * CXL) * HL + gy) * HL + gx;
                vv[2] = xl[xbase + (2 * br) * HL * HL];
                vv[3] = xl[xbase + (2 * br + 1) * HL * HL];
                vv[4] = mask[(b * HL + gy) * HL + gx];
                const float u = (vv[0] + vv[1] + vv[2] + vv[3] + vv[4]) * 0.2f;
                float var = 0.f;
                #pragma unroll
                for (int c = 0; c < 5; ++c) { const float d = vv[c] - u; var += d * d; }
                var *= 0.2f;
                const float rstd = rsqrtf(var + 1e-6f);
                #pragma unroll
                for (int c = 0; c < 5; ++c)
                    vv[c] = g_ln_w[br * 5 + c] * ((vv[c] - u) * rstd) + g_ln_b[br * 5 + c];
            }
            #pragma unroll
            for (int c = 0; c < 5; ++c) s_gln[c][ly][lx] = vv[c];
        }
        __syncthreads();

        // ---------- Phase 2: Haar DWT -> channel-interleaved subbands (b64 in, b128 out) ----------
        for (int idx = tid; idx < DT * DT; idx += 256) {
            const int l = idx / DT, m = idx % DT;
            float* dst = &s_un[(l * DT + m) * 20];
            #pragma unroll
            for (int c = 0; c < 5; ++c) {
                const float2 t0 = *(const float2*)&s_gln[c][2 * l][2 * m];
                const float2 t1 = *(const float2*)&s_gln[c][2 * l + 1][2 * m];
                const float a  = t0.x, b2 = t0.y, c2 = t1.x, d2 = t1.y;
                float4 sb;
                sb.x = 0.5f * (a + b2 + c2 + d2);   // LL
                sb.y = 0.5f * (a + b2 - c2 - d2);   // LH
                sb.z = 0.5f * (a - b2 + c2 - d2);   // HL
                sb.w = 0.5f * (a - b2 - c2 + d2);   // HH
                *(float4*)(dst + c * 4) = sb;
            }
        }
        __syncthreads();

        // ---------- Phase 3: depthwise 3x3 on 20 subbands via b128 reads ----------
        float tag[20];
        #pragma unroll
        for (int j = 0; j < 20; ++j) tag[j] = 0.f;
        const float* wb = g_wt_w + br * 180;
        #pragma unroll
        for (int dy = 0; dy < 3; ++dy) {
            #pragma unroll
            for (int dx = 0; dx < 3; ++dx) {
                const float* p = &s_un[((ty + dy) * DT + (tx + dx)) * 20];
                const float4 v0 = *(const float4*)(p);
                const float4 v1 = *(const float4*)(p + 4);
                const float4 v2 = *(const float4*)(p + 8);
                const float4 v3 = *(const float4*)(p + 12);
                const float4 v4 = *(const float4*)(p + 16);
                const int wo = dy * 3 + dx;
                tag[0]  += wb[0  * 9 + wo] * v0.x;  tag[1]  += wb[1  * 9 + wo] * v0.y;
                tag[2]  += wb[2  * 9 + wo] * v0.z;  tag[3]  += wb[3  * 9 + wo] * v0.w;
                tag[4]  += wb[4  * 9 + wo] * v1.x;  tag[5]  += wb[5  * 9 + wo] * v1.y;
                tag[6]  += wb[6  * 9 + wo] * v1.z;  tag[7]  += wb[7  * 9 + wo] * v1.w;
                tag[8]  += wb[8  * 9 + wo] * v2.x;  tag[9]  += wb[9  * 9 + wo] * v2.y;
                tag[10] += wb[10 * 9 + wo] * v2.z;  tag[11] += wb[11 * 9 + wo] * v2.w;
                tag[12] += wb[12 * 9 + wo] * v3.x;  tag[13] += wb[13 * 9 + wo] * v3.y;
                tag[14] += wb[14 * 9 + wo] * v3.z;  tag[15] += wb[15 * 9 + wo] * v3.w;
                tag[16] += wb[16 * 9 + wo] * v4.x;  tag[17] += wb[17 * 9 + wo] * v4.y;
                tag[18] += wb[18 * 9 + wo] * v4.z;  tag[19] += wb[19 * 9 + wo] * v4.w;
            }
        }
        #pragma unroll
        for (int j = 0; j < 20; ++j) tag[j] *= g_wt_s[br * 20 + j];

        // ---------- IDWT (thread-local 2x2 quad) ----------
        float xt[5][4];
        #pragma unroll
        for (int c = 0; c < 5; ++c) {
            const float LL = tag[c * 4 + 0], LH = tag[c * 4 + 1];
            const float HLv = tag[c * 4 + 2], HHv = tag[c * 4 + 3];
            xt[c][0] = 0.5f * (LL + LH + HLv + HHv);
            xt[c][1] = 0.5f * (LL + LH - HLv - HHv);
            xt[c][2] = 0.5f * (LL - LH + HLv - HHv);
            xt[c][3] = 0.5f * (LL - LH - HLv + HHv);
        }

        // ---------- Phase 4: base 3x3 dwconv via b64 4x6 patches ----------
        float gi[5][4];
        #pragma unroll
        for (int c = 0; c < 5; ++c) {
            float patch[4][6];
            #pragma unroll
            for (int r4 = 0; r4 < 4; ++r4) {
                const float* rp = &s_gln[c][2 * ty + 1 + r4][2 * tx];
                const float2 pa = *(const float2*)(rp);
                const float2 pb = *(const float2*)(rp + 2);
                const float2 pc = *(const float2*)(rp + 4);
                patch[r4][0] = pa.x; patch[r4][1] = pa.y;
                patch[r4][2] = pb.x; patch[r4][3] = pb.y;
                patch[r4][4] = pc.x; patch[r4][5] = pc.y;
            }
            const float* bw = g_base_w + br * 45 + c * 9;
            const float bb2 = g_base_b[br * 5 + c], bs = g_base_s[br * 5 + c];
            #pragma unroll
            for (int p = 0; p < 4; ++p) {
                const int py = p >> 1, px = p & 1;
                float acc = 0.f;
                #pragma unroll
                for (int dy = 0; dy < 3; ++dy)
                    #pragma unroll
                    for (int dx = 0; dx < 3; ++dx)
                        acc += bw[dy * 3 + dx] * patch[py + dy][1 + px + dx];
                gi[c][p] = (acc + bb2) * bs + xt[c][p];
            }
        }

        // ---------- 5x5 pointwise + tail accumulation ----------
        #pragma unroll
        for (int p = 0; p < 4; ++p) {
            #pragma unroll
            for (int o = 0; o < 5; ++o) {
                float v = 0.f;
                #pragma unroll
                for (int c = 0; c < 5; ++c) v += g_pw_w[br * 25 + o * 5 + c] * gi[c][p];
                const int cg = br * 5 + o;
                S1[p] += v;
                S2[p] += v * v;
                const float lw = tail_ln_w[cg];
                #pragma unroll
                for (int o8 = 0; o8 < 8; ++o8)
                    T[p][o8] += tail_w[o8 * 20 + cg] * lw * v;
            }
        }
        __syncthreads();   // before next branch overwrites s_gln / s_un
    }

    // ---------- Phase 5: tail LN (closed form) + 1x1 + GELU + residual ----------
    float A[8], Bc[8];
    #pragma unroll
    for (int o = 0; o < 8; ++o) {
        float a = 0.f, bb = tail_b[o];
        #pragma unroll
        for (int cg = 0; cg < 20; ++cg) {
            a  += tail_w[o * 20 + cg] * tail_ln_w[cg];
            bb += tail_w[o * 20 + cg] * tail_ln_b[cg];
        }
        A[o] = a; Bc[o] = bb;
    }

    #pragma unroll
    for (int p = 0; p < 4; ++p) {
        const int py = p >> 1, px = p & 1;
        const int gy = ty0 + 2 * ty + py, gx = tx0 + 2 * tx + px;
        const float u    = S1[p] * 0.05f;
        const float var  = S2[p] * 0.05f - u * u;
        const float rstd = rsqrtf(var + 1e-6f);

        const int xbase = ((b * CXL) * HL + gy) * HL + gx;
        float xlv[8];
        #pragma unroll
        for (int c = 0; c < 8; ++c) xlv[c] = xl[xbase + c * HL * HL];
        const float mk = mask[(b * HL + gy) * HL + gx];

        #pragma unroll
        for (int o = 0; o < 8; ++o) {
            const float val = (T[p][o] - u * A[o]) * rstd + Bc[o];
            const float g = gelu_exact(val);
            float r = res_b[o] + res_w[o * 9 + 8] * mk;
            #pragma unroll
            for (int c = 0; c < 8; ++c) r += res_w[o * 9 + c] * xlv[c];
            out[xbase + o * HL * HL] = g + r;
        }
    }
}

extern "C" void kernel_launch(void* const* d_in, const int* in_sizes, int n_in,
                              void* d_out, int out_size, void* d_ws, size_t ws_size,
                              hipStream_t stream) {
    (void)in_sizes; (void)out_size; (void)d_ws; (void)ws_size;
    if (n_in < 19) return;
    const float* xh        = (const float*)d_in[0];
    const float* xl        = (const float*)d_in[1];
    const float* mask      = (const float*)d_in[2];
    const float* pre_w     = (const float*)d_in[3];
    const float* pre_b     = (const float*)d_in[4];
    const float* g_ln_w    = (const float*)d_in[5];
    const float* g_ln_b    = (const float*)d_in[6];
    const float* g_base_w  = (const float*)d_in[7];
    const float* g_base_b  = (const float*)d_in[8];
    const float* g_base_s  = (const float*)d_in[9];
    const float* g_wt_w    = (const float*)d_in[10];
    const float* g_wt_s    = (const float*)d_in[11];
    const float* g_pw_w    = (const float*)d_in[12];
    const float* tail_ln_w = (const float*)d_in[13];
    const float* tail_ln_b = (const float*)d_in[14];
    const float* tail_w    = (const float*)d_in[15];
    const float* tail_b    = (const float*)d_in[16];
    const float* res_w     = (const float*)d_in[17];
    const float* res_b     = (const float*)d_in[18];
    float* outp = (float*)d_out;

    dim3 grid(HL / TS, HL / TS, BB);   // (16, 16, 8) = 2048 blocks
    dim3 block(16, 16, 1);             // 256 threads, each owns a 2x2 output quad
    uem_fused_kernel<<<grid, block, 0, stream>>>(
        xh, xl, mask, pre_w, pre_b, g_ln_w, g_ln_b, g_base_w, g_base_b,
        g_base_s, g_wt_w, g_wt_s, g_pw_w, tail_ln_w, tail_ln_b, tail_w,
        tail_b, res_w, res_b, outp);
}